// Round 3
// baseline (317.961 us; speedup 1.0000x reference)
//
#include <hip/hip_runtime.h>

// Problem constants (match reference)
constexpr int BB  = 8;
constexpr int NN  = 2048;
constexpr int IND = 128;
constexpr int HD  = 64;
constexpr float LN_EPS = 1e-5f;
constexpr float SLOPE  = 0.2f;

typedef _Float16 half8 __attribute__((ext_vector_type(8)));
typedef _Float16 half4 __attribute__((ext_vector_type(4)));
typedef float    f32x4 __attribute__((ext_vector_type(4)));

__device__ __forceinline__ float wave_sum(float v) {
    #pragma unroll
    for (int off = 32; off > 0; off >>= 1) v += __shfl_xor(v, off);
    return v;
}
__device__ __forceinline__ float wave_max(float v) {
    #pragma unroll
    for (int off = 32; off > 0; off >>= 1) v = fmaxf(v, __shfl_xor(v, off));
    return v;
}

// ---------------------------------------------------------------------------
// Kernel 1 (unchanged from R2): gated inputs, 8 rows per wave.
// Produces Wh (f32 output), Whh2 (fp16 k-packed [B][N/8][64][8]), Wh1, Wh2.
// ---------------------------------------------------------------------------
__global__ __launch_bounds__(256) void k_gates(
    const float* __restrict__ x, const float* __restrict__ h,
    const float* __restrict__ X2H, const float* __restrict__ H2H,
    const float* __restrict__ a,
    float* __restrict__ Wh_out, _Float16* __restrict__ Whh2,
    float* __restrict__ Wh1, float* __restrict__ Wh2)
{
    const int lane = threadIdx.x & 63;
    const int wid  = threadIdx.x >> 6;
    const int base = (blockIdx.x * 4 + wid) * 8;   // 8 rows per wave (one k-pack)

    float gx0[8] = {0}, gx1[8] = {0}, gx2[8] = {0};
    float gh0[8] = {0}, gh1[8] = {0}, gh2[8] = {0};

    for (int d4 = 0; d4 < IND; d4 += 4) {
        float w0[4], w1[4], w2[4];
        #pragma unroll
        for (int dd = 0; dd < 4; ++dd) {
            const float* wp = X2H + (size_t)(d4 + dd) * 192;
            w0[dd] = wp[lane]; w1[dd] = wp[64 + lane]; w2[dd] = wp[128 + lane];
        }
        #pragma unroll
        for (int rr = 0; rr < 8; ++rr) {
            f32x4 xv = *(const f32x4*)(x + (size_t)(base + rr) * IND + d4);
            #pragma unroll
            for (int dd = 0; dd < 4; ++dd) {
                gx0[rr] = fmaf(xv[dd], w0[dd], gx0[rr]);
                gx1[rr] = fmaf(xv[dd], w1[dd], gx1[rr]);
                gx2[rr] = fmaf(xv[dd], w2[dd], gx2[rr]);
            }
        }
    }
    for (int d4 = 0; d4 < HD; d4 += 4) {
        float w0[4], w1[4], w2[4];
        #pragma unroll
        for (int dd = 0; dd < 4; ++dd) {
            const float* wp = H2H + (size_t)(d4 + dd) * 192;
            w0[dd] = wp[lane]; w1[dd] = wp[64 + lane]; w2[dd] = wp[128 + lane];
        }
        #pragma unroll
        for (int rr = 0; rr < 8; ++rr) {
            f32x4 hv = *(const f32x4*)(h + (size_t)(base + rr) * HD + d4);
            #pragma unroll
            for (int dd = 0; dd < 4; ++dd) {
                gh0[rr] = fmaf(hv[dd], w0[dd], gh0[rr]);
                gh1[rr] = fmaf(hv[dd], w1[dd], gh1[rr]);
                gh2[rr] = fmaf(hv[dd], w2[dd], gh2[rr]);
            }
        }
    }

    const float a0 = a[lane], a1 = a[64 + lane];
    half8 p8;
    for (int rr = 0; rr < 8; ++rr) {
        const int row = base + rr;
        const float hr = h[(size_t)row * HD + lane];
        const float rg = 1.f / (1.f + __expf(-(gx0[rr] + gh0[rr])));
        const float ig = 1.f / (1.f + __expf(-(gx1[rr] + gh1[rr])));
        float irh = gx2[rr] + rg * gh2[rr];
        const float mu = wave_sum(irh) * (1.f / 64.f);
        const float dv = irh - mu;
        const float var = wave_sum(dv * dv) * (1.f / 64.f);
        const float ng = tanhf(dv * rsqrtf(var + LN_EPS));
        const float wh = ng + ig * (hr - ng);
        Wh_out[(size_t)row * HD + lane] = wh;
        p8[rr] = (_Float16)wh;
        const float d1 = wave_sum(wh * a0);
        const float d2 = wave_sum(wh * a1);
        if (lane == 0) { Wh1[row] = d1; Wh2[row] = d2; }
    }
    *(half8*)(Whh2 + ((size_t)(base >> 3) * 64 + lane) * 8) = p8;
}

// ---------------------------------------------------------------------------
// Kernel 2: fully wave-independent attention.  One 64-thread block = one wave
// owns 16 query rows end-to-end.  K is processed in 8 chunks of 256:
//   Phase A: adj(16 rows x 256) + scores -> P chunk (fp16) in wave-private LDS
//   Phase B: 4 col-chunks x 8 MFMA (16x16x32) accumulate
// No __syncthreads barriers survive codegen (1-wave workgroup => elided),
// no cross-wave data sharing, softmax shift c = lrelu(Wh1_row + max Wh2)
// computed entirely in-wave from the Wh2 register cache.
// ---------------------------------------------------------------------------
constexpr int KC   = 256;        // K-chunk
constexpr int PST  = KC + 8;     // fp16 row stride (pad: +16B keeps b128 2-way max)
constexpr int NCHK = NN / KC;    // 8

__global__ __launch_bounds__(64, 1) void k_attn(
    const int* __restrict__ adj,
    const _Float16* __restrict__ Whh2,   // [B][N/8][64][8]
    const float* __restrict__ Wh1, const float* __restrict__ Wh2,
    float* __restrict__ hp)
{
    __shared__ __align__(16) _Float16 Pbuf[16 * PST];   // 8448 B, wave-private

    const int lane = threadIdx.x;            // 0..63
    const int b    = blockIdx.x >> 7;        // 128 row-groups per batch
    const int i0   = (blockIdx.x & 127) * 16;
    const int m    = lane & 15;
    const int q    = lane >> 4;

    // Wh2 register cache: wv[c][d] = Wh2[b][c*256 + 4*lane + d]  (full row)
    f32x4 wv[8];
    const f32x4* __restrict__ w2v = (const f32x4*)(Wh2 + (size_t)b * NN);
    #pragma unroll
    for (int k = 0; k < 8; ++k) wv[k] = w2v[lane + 64 * k];

    // batch-wide max of Wh2 — wave-local (wave holds all 2048 values)
    float mx = -3e38f;
    #pragma unroll
    for (int k = 0; k < 8; ++k)
        mx = fmaxf(mx, fmaxf(fmaxf(wv[k][0], wv[k][1]), fmaxf(wv[k][2], wv[k][3])));
    const float M = wave_max(mx);

    // per-row Wh1 and softmax shift (uniform scalar loads)
    float w1r[16], cr[16];
    #pragma unroll
    for (int r = 0; r < 16; ++r) {
        w1r[r] = Wh1[b * NN + i0 + r];
        const float t0 = w1r[r] + M;
        cr[r] = (t0 > 0.f) ? t0 : SLOPE * t0;   // exact row upper bound
    }

    const int* __restrict__ abase = adj + ((size_t)b * NN + i0) * NN;
    const half8* __restrict__ Wp  = (const half8*)(Whh2 + (size_t)b * NN * HD);

    float sacc[16];
    #pragma unroll
    for (int r = 0; r < 16; ++r) sacc[r] = 0.f;
    f32x4 acc[4];
    #pragma unroll
    for (int cc = 0; cc < 4; ++cc) acc[cc] = (f32x4){0.f, 0.f, 0.f, 0.f};

    int4 av[16];
    #pragma unroll
    for (int r = 0; r < 16; ++r)
        av[r] = *(const int4*)(abase + (size_t)r * NN + lane * 4);

    for (int c = 0; c < NCHK; ++c) {
        // ---- Phase A: P chunk into wave-private LDS ----
        #pragma unroll
        for (int r = 0; r < 16; ++r) {
            const int ai[4] = {av[r].x, av[r].y, av[r].z, av[r].w};
            half4 ph;
            float s = 0.f;
            #pragma unroll
            for (int d = 0; d < 4; ++d) {
                const float t = w1r[r] + wv[c][d];
                const float e = (t > 0.f) ? t : SLOPE * t;
                const float p = ai[d] ? __expf(e - cr[r]) : 0.f;
                s += p;
                ph[d] = (_Float16)p;
            }
            sacc[r] += s;
            *(half4*)&Pbuf[r * PST + 4 * lane] = ph;     // ds_write_b64
        }
        // prefetch next chunk's adj while MFMA section runs
        if (c + 1 < NCHK) {
            #pragma unroll
            for (int r = 0; r < 16; ++r)
                av[r] = *(const int4*)(abase + (size_t)r * NN + (c + 1) * KC + lane * 4);
        }
        __syncthreads();   // 1-wave workgroup: elided to waitcnt, orders LDS

        // ---- Phase B: 16x64 += P[16 x 256] @ Wh[256 x 64] ----
        #pragma unroll
        for (int cc = 0; cc < 4; ++cc) {
            #pragma unroll
            for (int k8 = 0; k8 < 8; ++k8) {
                const half8 a8 = *(const half8*)&Pbuf[m * PST + k8 * 32 + q * 8];
                const half8 b8 = Wp[(size_t)(c * 32 + k8 * 4 + q) * 64 + cc * 16 + m];
                acc[cc] = __builtin_amdgcn_mfma_f32_16x16x32_f16(a8, b8, acc[cc], 0, 0, 0);
            }
        }
        __syncthreads();   // elided; WAR guard before next chunk's writes
    }

    // ---- epilogue: row sums + scaled store ----
    float linv[16];
    #pragma unroll
    for (int r = 0; r < 16; ++r) linv[r] = 1.f / wave_sum(sacc[r]);

    #pragma unroll
    for (int cc = 0; cc < 4; ++cc) {
        #pragma unroll
        for (int r2 = 0; r2 < 4; ++r2) {
            // l = linv[q*4 + r2], q runtime -> 3 selects
            float l = (q == 0) ? linv[r2]
                    : (q == 1) ? linv[4 + r2]
                    : (q == 2) ? linv[8 + r2]
                               : linv[12 + r2];
            const int irow = q * 4 + r2;
            hp[((size_t)b * NN + i0 + irow) * HD + cc * 16 + m] = acc[cc][r2] * l;
        }
    }
}

// ---------------------------------------------------------------------------
extern "C" void kernel_launch(void* const* d_in, const int* in_sizes, int n_in,
                              void* d_out, int out_size, void* d_ws, size_t ws_size,
                              hipStream_t stream) {
    const int*   adj = (const int*)d_in[0];
    const float* x   = (const float*)d_in[1];
    const float* h   = (const float*)d_in[2];
    const float* X2H = (const float*)d_in[3];
    const float* H2H = (const float*)d_in[4];
    const float* a   = (const float*)d_in[5];

    float* out = (float*)d_out;
    float* hp  = out;                              // h_prime [8][2048][64]
    float* Wh  = out + (size_t)BB * NN * HD;       // Wh      [8][2048][64]

    float*    Wh1  = (float*)d_ws;                 // [B*N]
    float*    Wh2  = Wh1 + BB * NN;                // [B*N]
    _Float16* Whh2 = (_Float16*)(Wh2 + BB * NN);   // [B][N/8][64][8] fp16

    k_gates<<<dim3((BB * NN) / 32), dim3(256), 0, stream>>>(
        x, h, X2H, H2H, a, Wh, Whh2, Wh1, Wh2);
    k_attn<<<dim3(BB * (NN / 16)), dim3(64), 0, stream>>>(
        adj, Whh2, Wh1, Wh2, hp);
}